// Round 4
// baseline (150.559 us; speedup 1.0000x reference)
//
#include <hip/hip_runtime.h>
#include <hip/hip_bf16.h>
#include <math.h>

#define EPS 1e-8f
#define BB 32
#define SS 64
#define HH 200
#define LL 20
#define KST 232   // bf16 LDS row stride
#define SST 68    // S-tile LDS row stride (floats)
#define MHS 200   // mean/max LDS row stride (floats)

typedef short bf16x8 __attribute__((ext_vector_type(8)));
typedef float f32x4 __attribute__((ext_vector_type(4)));

__device__ inline float bf2f(short u) {
    union { unsigned int i; float f; } v;
    v.i = ((unsigned int)(unsigned short)u) << 16;
    return v.f;
}

// ONE kernel, grid 2304 x 512 (= 256 groups of 9: 4 type-A + 5 type-C). No workspace.
//   type A (1024): 8 self-rows: att S + attvec (mean/max LDS f32) + matches m=0,1,2
//   type C (1280): pairwise MFMA, two-pass over B halves (r3 math verbatim)
//
// Type A LDS (floats, 12176 = 48.7 KB -> 3 blocks/CU):
//   [0,928)       AT 8xKST bf16       \ overlay PB 24xKST bf16 [0,2784)
//   [928,8352)    BT 64xKST bf16      /         WB 32xKST bf16 [2784,6496)
//   [8352,8896)   S_L 8xSST f32
//   [8896,8976)   nrmA(8) nrmB(64) dsum(8)
//   [8976,10576)  meanL 8x200 f32
//   [10576,12176) maxL  8x200 f32
// Type C LDS: AT 64xKST [0,7424) | BTh 32xKST [7424,11136) | cmL [11136,11264)
//             nA [11264,11328) | nB [11328,11392)
__global__ __launch_bounds__(512) void fused_all_kernel(
        const float* __restrict__ conp, const float* __restrict__ conh,
        const float* __restrict__ w1, const float* __restrict__ w2,
        const float* __restrict__ w3, const float* __restrict__ w4,
        const float* __restrict__ w5, const float* __restrict__ w6,
        const float* __restrict__ w7, const float* __restrict__ w8,
        float* __restrict__ out) {
    __shared__ __align__(16) float smem[12176];
    int t = threadIdx.x;

    // interleave: group of 9 blocks = 4 type-A + 5 type-C
    int grp = blockIdx.x / 9;
    int rem = blockIdx.x % 9;

    if (rem < 4) {
        // ================================ type A (8 self-rows)
        __hip_bfloat16* AT = (__hip_bfloat16*)smem;
        __hip_bfloat16* BT = (__hip_bfloat16*)(smem + 928);
        float* S_L  = smem + 8352;
        float* nrmA = smem + 8896;
        float* nrmB = smem + 8904;
        float* dsum = smem + 8968;
        __hip_bfloat16* PB = (__hip_bfloat16*)smem;            // phase 3: 24xKST
        __hip_bfloat16* WB = (__hip_bfloat16*)(smem + 2784);   // phase 3: 32xKST
        float* meanL = smem + 8976;
        float* maxL  = smem + 10576;

        int blk = grp * 4 + rem;       // 0..1023
        int qh = blk & 7;              // 8-row eighth of self side
        int sdb = blk >> 3;
        int b = sdb & 31, sd = sdb >> 5;
        int dir = sd & 1, side = sd >> 1;
        const float* selfb = side ? conh : conp;
        const float* oppb  = side ? conp : conh;

        if (t < 8) nrmA[t] = 0.f;
        if (t < 64) nrmB[t] = 0.f;
        __syncthreads();

        // ---- phase 1: stage 8 self rows (AT) + 64 opp rows (BT); atomic norms
        for (int e = t; e < 8 * 28; e += 512) {
            int sl = e / 28, ck = e % 28, k = ck * 8;
            __align__(16) __hip_bfloat16 r8[8];
            if (k < HH) {
                const float* xp = selfb + (b * SS + qh * 8 + sl) * (2 * HH) + dir * HH + k;
                float xv[8];
                *(float4*)&xv[0] = *(const float4*)xp; *(float4*)&xv[4] = *(const float4*)(xp + 4);
                float ss = 0.f;
#pragma unroll
                for (int i = 0; i < 8; ++i) { r8[i] = __float2bfloat16(xv[i]); ss = fmaf(xv[i], xv[i], ss); }
                atomicAdd(&nrmA[sl], ss);
            } else {
#pragma unroll
                for (int i = 0; i < 8; ++i) r8[i] = __float2bfloat16(0.f);
            }
            *(bf16x8*)&AT[sl * KST + k] = *(bf16x8*)r8;
        }
        for (int e = t; e < 64 * 28; e += 512) {
            int rw = e / 28, ck = e % 28, k = ck * 8;
            __align__(16) __hip_bfloat16 r8[8];
            if (k < HH) {
                const float* xp = oppb + (b * SS + rw) * (2 * HH) + dir * HH + k;
                float xv[8];
                *(float4*)&xv[0] = *(const float4*)xp; *(float4*)&xv[4] = *(const float4*)(xp + 4);
                float ss = 0.f;
#pragma unroll
                for (int i = 0; i < 8; ++i) { r8[i] = __float2bfloat16(xv[i]); ss = fmaf(xv[i], xv[i], ss); }
                atomicAdd(&nrmB[rw], ss);
            } else {
#pragma unroll
                for (int i = 0; i < 8; ++i) r8[i] = __float2bfloat16(0.f);
            }
            *(bf16x8*)&BT[rw * KST + k] = *(bf16x8*)r8;
        }
        __syncthreads();

        int wv_ = __builtin_amdgcn_readfirstlane(t >> 6);
        int lane = t & 63;
        int q = lane >> 4, c = lane & 15;

        // ---- S = cos(A,B): 8x64 via 4 16x16 tiles (rows >= 8 discarded), waves 0-3
        if (wv_ < 4) {
            int ct = wv_;
            f32x4 acc = (f32x4){0.f, 0.f, 0.f, 0.f};
            for (int ks = 0; ks < 7; ++ks) {
                int kb = ks * 32 + q * 8;
                bf16x8 af  = *(const bf16x8*)&AT[c * KST + kb];   // c>=8 reads BT rows: defined, discarded
                bf16x8 bf_ = *(const bf16x8*)&BT[(ct * 16 + c) * KST + kb];
                acc = __builtin_amdgcn_mfma_f32_16x16x32_bf16(af, bf_, acc, 0, 0, 0);
            }
            if (q < 2) {   // rows 0..7 only
                int col = ct * 16 + c;
                float no = sqrtf(nrmB[col]);
#pragma unroll
                for (int r = 0; r < 4; ++r) {
                    int row = q * 4 + r;
                    float ns = sqrtf(nrmA[row]);
                    S_L[row * SST + col] = acc[r] / fmaxf(ns * no, EPS);
                }
            }
        }
        __syncthreads();

        if (t < 8) {
            float sm = 0.f;
            for (int k = 0; k < 64; ++k) sm += S_L[t * SST + k];
            dsum[t] = fmaxf(sm, EPS);
        }
        __syncthreads();

        // ---- phase 2: attvec -> meanL / maxL (f32, in LDS)
        for (int e = t; e < 8 * 25; e += 512) {
            int s = e / 25, hc = e % 25, h0 = hc * 8;
            float dsv = dsum[s];
            float ms[8], mx[8];
#pragma unroll
            for (int i = 0; i < 8; ++i) { ms[i] = 0.f; mx[i] = -INFINITY; }
            for (int k = 0; k < 64; ++k) {
                float a = S_L[s * SST + k];
                bf16x8 ov = *(const bf16x8*)&BT[k * KST + h0];
#pragma unroll
                for (int i = 0; i < 8; ++i) {
                    float tt = a * bf2f(ov[i]);
                    ms[i] += tt;
                    mx[i] = fmaxf(mx[i], tt);
                }
            }
#pragma unroll
            for (int i = 0; i < 8; ++i) ms[i] /= dsv;
            *(float4*)&meanL[s * MHS + h0]     = *(float4*)&ms[0];
            *(float4*)&meanL[s * MHS + h0 + 4] = *(float4*)&ms[4];
            *(float4*)&maxL[s * MHS + h0]      = *(float4*)&mx[0];
            *(float4*)&maxL[s * MHS + h0 + 4]  = *(float4*)&mx[4];
        }
        __syncthreads();   // PB/WB overlays about to overwrite AT/BT

        // ---- phase 3: matches m=0 (full), m=1 (att_mean), m=2 (att_max)
        int fidx = dir ? 0 : (SS - 1);
        const float* fvr = oppb + (b * SS + fidx) * (2 * HH) + dir * HH;
        for (int m = 0; m < 3; ++m) {
            const float* wsrc = (m == 0) ? (dir ? w2 : w1)
                              : (m == 1) ? (dir ? w6 : w5)
                                         : (dir ? w8 : w7);
            // stage products [x^2 ; x*y ; y^2] (x^2 persists from m=0)
            for (int e = t; e < 8 * 28; e += 512) {
                int sl = e / 28, ck = e % 28, k = ck * 8;
                __align__(16) __hip_bfloat16 r0[8], r1[8], r2[8];
                if (k < HH) {
                    const float* xp = selfb + (b * SS + qh * 8 + sl) * (2 * HH) + dir * HH + k;
                    float xv[8], yv[8];
                    *(float4*)&xv[0] = *(const float4*)xp; *(float4*)&xv[4] = *(const float4*)(xp + 4);
                    if (m == 0) {
                        *(float4*)&yv[0] = *(const float4*)(fvr + k);
                        *(float4*)&yv[4] = *(const float4*)(fvr + k + 4);
                    } else {
                        const float* yL = (m == 1 ? meanL : maxL) + sl * MHS + k;
                        *(float4*)&yv[0] = *(const float4*)yL;
                        *(float4*)&yv[4] = *(const float4*)(yL + 4);
                    }
#pragma unroll
                    for (int i = 0; i < 8; ++i) {
                        if (m == 0) r0[i] = __float2bfloat16(xv[i] * xv[i]);
                        r1[i] = __float2bfloat16(xv[i] * yv[i]);
                        r2[i] = __float2bfloat16(yv[i] * yv[i]);
                    }
                } else {
#pragma unroll
                    for (int i = 0; i < 8; ++i) {
                        r0[i] = __float2bfloat16(0.f); r1[i] = __float2bfloat16(0.f); r2[i] = __float2bfloat16(0.f);
                    }
                }
                if (m == 0) *(bf16x8*)&PB[(0 * 8 + sl) * KST + k] = *(bf16x8*)r0;
                *(bf16x8*)&PB[(1 * 8 + sl) * KST + k] = *(bf16x8*)r1;
                *(bf16x8*)&PB[(2 * 8 + sl) * KST + k] = *(bf16x8*)r2;
            }
            // stage w^2 (rows >= 20 zero)
            for (int e = t; e < 32 * 28; e += 512) {
                int l_ = e / 28, ck = e % 28, k = ck * 8;
                __align__(16) __hip_bfloat16 wr[8];
                if (l_ < LL && k < HH) {
                    const float* wp = wsrc + l_ * HH + k;
                    float wv[8];
                    *(float4*)&wv[0] = *(const float4*)wp; *(float4*)&wv[4] = *(const float4*)(wp + 4);
#pragma unroll
                    for (int i = 0; i < 8; ++i) wr[i] = __float2bfloat16(wv[i] * wv[i]);
                } else {
#pragma unroll
                    for (int i = 0; i < 8; ++i) wr[i] = __float2bfloat16(0.f);
                }
                *(bf16x8*)&WB[l_ * KST + k] = *(bf16x8*)wr;
            }
            __syncthreads();

            if (wv_ < 2) {
                int ntile = wv_;
                f32x4 accA = (f32x4){0.f, 0.f, 0.f, 0.f};
                f32x4 accD = (f32x4){0.f, 0.f, 0.f, 0.f};
                f32x4 accB = (f32x4){0.f, 0.f, 0.f, 0.f};
                for (int ks = 0; ks < 7; ++ks) {
                    int kb = ks * 32 + q * 8;
                    bf16x8 bfw = *(const bf16x8*)&WB[(ntile * 16 + c) * KST + kb];
                    bf16x8 a0 = *(const bf16x8*)&PB[(0 * 8 + c) * KST + kb];   // c>=8 bleeds to next set: discarded rows
                    bf16x8 a1 = *(const bf16x8*)&PB[(1 * 8 + c) * KST + kb];
                    bf16x8 a2 = *(const bf16x8*)&PB[(2 * 8 + c) * KST + kb];
                    accA = __builtin_amdgcn_mfma_f32_16x16x32_bf16(a0, bfw, accA, 0, 0, 0);
                    accD = __builtin_amdgcn_mfma_f32_16x16x32_bf16(a1, bfw, accD, 0, 0, 0);
                    accB = __builtin_amdgcn_mfma_f32_16x16x32_bf16(a2, bfw, accB, 0, 0, 0);
                }
                int l_ = ntile * 16 + c;
                if (l_ < LL && q < 2) {   // rows 0..7 only
                    int chunk = (m == 0) ? 0 : (m == 1) ? 40 : 60;
#pragma unroll
                    for (int r = 0; r < 4; ++r) {
                        int s = qh * 8 + q * 4 + r;
                        float cosv = accD[r] / fmaxf(sqrtf(accA[r] * accB[r]), EPS);
                        out[side * (BB * SS * 160) + (b * SS + s) * 160 + dir * 80 + chunk + l_] = cosv;
                    }
                }
            }
            if (m < 2) __syncthreads();
        }
    } else {
        // ================================ type C: pairwise bf16 MFMA, two-pass B halves
        __hip_bfloat16* AT  = (__hip_bfloat16*)smem;            // 64xKST
        __hip_bfloat16* BTh = (__hip_bfloat16*)(smem + 7424);   // 32xKST
        float* cmL = smem + 11136;                              // 128
        float* nA  = smem + 11264;                              // 64
        float* nB  = smem + 11328;                              // 64
        int blk = grp * 5 + (rem - 4);   // 0..1279
        int l = blk % LL; int db = blk / LL; int b = db & 31; int dir = db >> 5;

        const float* wrow = (dir ? w4 : w3) + l * HH;
        const float* Ag = conp + dir * HH;
        const float* Bg = conh + dir * HH;

        if (t < 64) { nA[t] = 0.f; nB[t] = 0.f; }
        __syncthreads();

        // stage A (64 rows)
        for (int e = t; e < 64 * 28; e += 512) {
            int m = e / 28, ck = e - m * 28;
            int k = ck * 8;
            __align__(16) __hip_bfloat16 at8[8];
            if (k < HH) {
                const float* ap = Ag + (b * SS + m) * (2 * HH) + k;
                const float* wp = wrow + k;
                float av[8], wvv[8];
                *(float4*)&av[0]  = *(const float4*)ap; *(float4*)&av[4]  = *(const float4*)(ap + 4);
                *(float4*)&wvv[0] = *(const float4*)wp; *(float4*)&wvv[4] = *(const float4*)(wp + 4);
                float ssa = 0.f;
#pragma unroll
                for (int i = 0; i < 8; ++i) {
                    float aw = av[i] * wvv[i];
                    at8[i] = __float2bfloat16(aw);
                    ssa = fmaf(aw, aw, ssa);
                }
                atomicAdd(&nA[m], ssa);
            } else {
#pragma unroll
                for (int ii = 0; ii < 8; ++ii) at8[ii] = __float2bfloat16(0.f);
            }
            *(bf16x8*)&AT[m * KST + k] = *(bf16x8*)at8;
        }
        // stage B half 0 (rows 0..31)
        for (int e = t; e < 32 * 28; e += 512) {
            int rw = e / 28, ck = e - rw * 28;
            int k = ck * 8;
            __align__(16) __hip_bfloat16 bt8[8];
            if (k < HH) {
                const float* bp = Bg + (b * SS + rw) * (2 * HH) + k;
                const float* wp = wrow + k;
                float bv[8], wvv[8];
                *(float4*)&bv[0]  = *(const float4*)bp; *(float4*)&bv[4]  = *(const float4*)(bp + 4);
                *(float4*)&wvv[0] = *(const float4*)wp; *(float4*)&wvv[4] = *(const float4*)(wp + 4);
                float ssb = 0.f;
#pragma unroll
                for (int i = 0; i < 8; ++i) {
                    float bw = bv[i] * wvv[i];
                    bt8[i] = __float2bfloat16(bw);
                    ssb = fmaf(bw, bw, ssb);
                }
                atomicAdd(&nB[rw], ssb);
            } else {
#pragma unroll
                for (int ii = 0; ii < 8; ++ii) bt8[ii] = __float2bfloat16(0.f);
            }
            *(bf16x8*)&BTh[rw * KST + k] = *(bf16x8*)bt8;
        }
        __syncthreads();

        int wv_ = __builtin_amdgcn_readfirstlane(t >> 6);
        int lane = t & 63;
        int q = lane >> 4, c = lane & 15;
        int m0 = wv_ * 16;

        float rowm[4] = {-INFINITY, -INFINITY, -INFINITY, -INFINITY};

        for (int h = 0; h < 2; ++h) {
            if (wv_ < 4) {
                f32x4 acc[2];
                acc[0] = (f32x4){0.f, 0.f, 0.f, 0.f};
                acc[1] = (f32x4){0.f, 0.f, 0.f, 0.f};
                for (int ks = 0; ks < 7; ++ks) {
                    int kb = ks * 32 + q * 8;
                    bf16x8 af = *(const bf16x8*)&AT[(m0 + c) * KST + kb];
#pragma unroll
                    for (int ctl = 0; ctl < 2; ++ctl) {
                        bf16x8 bf_ = *(const bf16x8*)&BTh[(ctl * 16 + c) * KST + kb];
                        acc[ctl] = __builtin_amdgcn_mfma_f32_16x16x32_bf16(af, bf_, acc[ctl], 0, 0, 0);
                    }
                }

                float na[4], nb2[2];
#pragma unroll
                for (int r = 0; r < 4; ++r) na[r] = sqrtf(nA[m0 + q * 4 + r]);
#pragma unroll
                for (int ctl = 0; ctl < 2; ++ctl) nb2[ctl] = sqrtf(nB[h * 32 + ctl * 16 + c]);

                float colm[2] = {-INFINITY, -INFINITY};
#pragma unroll
                for (int ctl = 0; ctl < 2; ++ctl) {
#pragma unroll
                    for (int r = 0; r < 4; ++r) {
                        float cv = acc[ctl][r] / fmaxf(na[r] * nb2[ctl], EPS);
                        rowm[r] = fmaxf(rowm[r], cv);
                        colm[ctl] = fmaxf(colm[ctl], cv);
                    }
                }
#pragma unroll
                for (int ctl = 0; ctl < 2; ++ctl) {
                    float v = colm[ctl];
                    v = fmaxf(v, __shfl_xor(v, 16, 64));
                    v = fmaxf(v, __shfl_xor(v, 32, 64));
                    colm[ctl] = v;
                }
                if (q == 0) {
#pragma unroll
                    for (int ctl = 0; ctl < 2; ++ctl) cmL[wv_ * 32 + ctl * 16 + c] = colm[ctl];
                }
            }
            __syncthreads();
            if (t < 32) {
                float mm = fmaxf(fmaxf(cmL[t], cmL[32 + t]), fmaxf(cmL[64 + t], cmL[96 + t]));
                out[BB * SS * 160 + (b * SS + h * 32 + t) * 160 + dir * 80 + 20 + l] = mm;
            }
            if (h == 0) {
                // stage B half 1 (rows 32..63)
                for (int e = t; e < 32 * 28; e += 512) {
                    int rw = e / 28, ck = e - rw * 28;
                    int k = ck * 8;
                    __align__(16) __hip_bfloat16 bt8[8];
                    if (k < HH) {
                        const float* bp = Bg + (b * SS + 32 + rw) * (2 * HH) + k;
                        const float* wp = wrow + k;
                        float bv[8], wvv[8];
                        *(float4*)&bv[0]  = *(const float4*)bp; *(float4*)&bv[4]  = *(const float4*)(bp + 4);
                        *(float4*)&wvv[0] = *(const float4*)wp; *(float4*)&wvv[4] = *(const float4*)(wp + 4);
                        float ssb = 0.f;
#pragma unroll
                        for (int i = 0; i < 8; ++i) {
                            float bw = bv[i] * wvv[i];
                            bt8[i] = __float2bfloat16(bw);
                            ssb = fmaf(bw, bw, ssb);
                        }
                        atomicAdd(&nB[32 + rw], ssb);
                    } else {
#pragma unroll
                        for (int ii = 0; ii < 8; ++ii) bt8[ii] = __float2bfloat16(0.f);
                    }
                    *(bf16x8*)&BTh[rw * KST + k] = *(bf16x8*)bt8;
                }
                __syncthreads();
            }
        }

        if (wv_ < 4) {
#pragma unroll
            for (int r = 0; r < 4; ++r) {
                float v = rowm[r];
                v = fmaxf(v, __shfl_xor(v, 1, 64));
                v = fmaxf(v, __shfl_xor(v, 2, 64));
                v = fmaxf(v, __shfl_xor(v, 4, 64));
                v = fmaxf(v, __shfl_xor(v, 8, 64));
                rowm[r] = v;
            }
            if (c == 0) {
#pragma unroll
                for (int r = 0; r < 4; ++r) {
                    int i = m0 + q * 4 + r;
                    out[(b * SS + i) * 160 + dir * 80 + 20 + l] = rowm[r];
                }
            }
        }
    }
}

extern "C" void kernel_launch(void* const* d_in, const int* in_sizes, int n_in,
                              void* d_out, int out_size, void* d_ws, size_t ws_size,
                              hipStream_t stream) {
    const float* conp = (const float*)d_in[0];
    const float* conh = (const float*)d_in[1];
    const float* w1 = (const float*)d_in[2];
    const float* w2 = (const float*)d_in[3];
    const float* w3 = (const float*)d_in[4];
    const float* w4 = (const float*)d_in[5];
    const float* w5 = (const float*)d_in[6];
    const float* w6 = (const float*)d_in[7];
    const float* w7 = (const float*)d_in[8];
    const float* w8 = (const float*)d_in[9];
    float* out = (float*)d_out;
    (void)d_ws; (void)ws_size;

    fused_all_kernel<<<2304, 512, 0, stream>>>(conp, conh,
                                               w1, w2, w3, w4, w5, w6, w7, w8, out);
}

// Round 5
// 116.541 us; speedup vs baseline: 1.2919x; 1.2919x over previous
//
#include <hip/hip_runtime.h>
#include <hip/hip_bf16.h>
#include <math.h>

#define EPS 1e-8f
#define BB 32
#define SS 64
#define HH 200
#define LL 20
#define KST 232   // bf16 LDS row stride
#define SST 68    // S-tile LDS row stride (floats)
#define MHS 200   // mean/max LDS row stride (floats)

typedef short bf16x8 __attribute__((ext_vector_type(8)));
typedef float f32x4 __attribute__((ext_vector_type(4)));

__device__ inline float bf2f(short u) {
    union { unsigned int i; float f; } v;
    v.i = ((unsigned int)(unsigned short)u) << 16;
    return v.f;
}

// ONE kernel, grid 1792 x 512 (256 groups of 7: 2 type-A + 5 type-C). No workspace.
//   type A (512): 16 self-rows: att S + attvec + matches m=0,1,2. Norms via MFMA diag
//                 (waves 4-7), dsum folded into phase 2, phase-3 globals prefetched.
//   type C (1280): pairwise MFMA; norms via MFMA diag (waves 4-7); no atomics.
//
// Type A LDS (floats, 19392 = 77.6 KB -> 2 blocks/CU):
//   [0,1856)       AT 16xKST bf16      \ overlay PB 48xKST bf16 [0,5568)
//   [1856,9280)    BT 64xKST bf16      /
//   [9280,10368)   S_L 16xSST f32      \ overlay WB 32xKST bf16 [9280,12992)
//   [10368,10448)  nrmA(16) nrmB(64)   /
//   [12992,16192)  meanL 16x200 f32
//   [16192,19392)  maxL  16x200 f32
// Type C LDS: AT 64xKST [0,7424) | BT [7424,14848) | cmL [14848,15104)
//             nA [15104,15168) | nB [15168,15232)
__global__ __launch_bounds__(512) void fused_all_kernel(
        const float* __restrict__ conp, const float* __restrict__ conh,
        const float* __restrict__ w1, const float* __restrict__ w2,
        const float* __restrict__ w3, const float* __restrict__ w4,
        const float* __restrict__ w5, const float* __restrict__ w6,
        const float* __restrict__ w7, const float* __restrict__ w8,
        float* __restrict__ out) {
    __shared__ __align__(16) float smem[19392];
    int t = threadIdx.x;

    int grp = blockIdx.x / 7;
    int rem = blockIdx.x % 7;

    if (rem < 2) {
        // ================================ type A (16 self-rows)
        __hip_bfloat16* AT = (__hip_bfloat16*)smem;
        __hip_bfloat16* BT = (__hip_bfloat16*)(smem + 1856);
        float* S_L  = smem + 9280;
        float* nrmA = smem + 10368;
        float* nrmB = smem + 10384;
        __hip_bfloat16* PB = (__hip_bfloat16*)smem;            // phase 3: 48xKST
        __hip_bfloat16* WB = (__hip_bfloat16*)(smem + 9280);   // phase 3: 32xKST
        float* meanL = smem + 12992;
        float* maxL  = smem + 16192;

        int blk = grp * 2 + rem;       // 0..511
        int qh = blk & 3;              // 16-row quarter of self side
        int sdb = blk >> 2;
        int b = sdb & 31, sd = sdb >> 5;
        int dir = sd & 1, side = sd >> 1;
        const float* selfb = side ? conh : conp;
        const float* oppb  = side ? conp : conh;
        int fidx = dir ? 0 : (SS - 1);
        const float* fvr = oppb + (b * SS + fidx) * (2 * HH) + dir * HH;

        int arow = t / 25, ack = t % 25;   // phase-1/2/3 mapping for t<400 / t<500

        // ---- phase 1: stage 16 self rows (regs kept) + fvr prefetch + 64 opp rows + pads
        float xr[8], yv0[8];
        if (t < 400) {
            const float* xp = selfb + (b * SS + qh * 16 + arow) * (2 * HH) + dir * HH + ack * 8;
            *(float4*)&xr[0] = *(const float4*)xp; *(float4*)&xr[4] = *(const float4*)(xp + 4);
            *(float4*)&yv0[0] = *(const float4*)(fvr + ack * 8);
            *(float4*)&yv0[4] = *(const float4*)(fvr + ack * 8 + 4);
            __align__(16) __hip_bfloat16 r8[8];
#pragma unroll
            for (int i = 0; i < 8; ++i) r8[i] = __float2bfloat16(xr[i]);
            *(bf16x8*)&AT[arow * KST + ack * 8] = *(bf16x8*)r8;
        }
        {
            __align__(16) __hip_bfloat16 z8[8];
#pragma unroll
            for (int i = 0; i < 8; ++i) z8[i] = __float2bfloat16(0.f);
            // pads: AT rows 0-15 ck 25-27 (48) + BT rows 0-63 ck 25-27 (192)
            if (t < 240) {
                if (t < 48) { int row = t / 3, ckp = 25 + t % 3;
                    *(bf16x8*)&AT[row * KST + ckp * 8] = *(bf16x8*)z8;
                } else { int e2 = t - 48; int row = e2 / 3, ckp = 25 + e2 % 3;
                    *(bf16x8*)&BT[row * KST + ckp * 8] = *(bf16x8*)z8;
                }
            }
        }
        for (int e = t; e < 1600; e += 512) {
            int rw = e / 25, ck = e % 25, k = ck * 8;
            const float* xp = oppb + (b * SS + rw) * (2 * HH) + dir * HH + k;
            float xv[8];
            *(float4*)&xv[0] = *(const float4*)xp; *(float4*)&xv[4] = *(const float4*)(xp + 4);
            __align__(16) __hip_bfloat16 r8[8];
#pragma unroll
            for (int i = 0; i < 8; ++i) r8[i] = __float2bfloat16(xv[i]);
            *(bf16x8*)&BT[rw * KST + k] = *(bf16x8*)r8;
        }
        __syncthreads();   // B1

        int wv_ = __builtin_amdgcn_readfirstlane(t >> 6);
        int lane = t & 63;
        int q = lane >> 4, c = lane & 15;

        // ---- MFMA: waves 0-3 raw S-tiles; waves 4-7 norm diagonals
        if (wv_ < 4) {
            int ct = wv_;
            f32x4 acc = (f32x4){0.f, 0.f, 0.f, 0.f};
            for (int ks = 0; ks < 7; ++ks) {
                int kb = ks * 32 + q * 8;
                bf16x8 af  = *(const bf16x8*)&AT[c * KST + kb];
                bf16x8 bf_ = *(const bf16x8*)&BT[(ct * 16 + c) * KST + kb];
                acc = __builtin_amdgcn_mfma_f32_16x16x32_bf16(af, bf_, acc, 0, 0, 0);
            }
            int col = ct * 16 + c;
#pragma unroll
            for (int r = 0; r < 4; ++r) S_L[(q * 4 + r) * SST + col] = acc[r];   // raw dot
        } else {
            int dt = wv_ - 4;
            f32x4 accB = (f32x4){0.f, 0.f, 0.f, 0.f};
            for (int ks = 0; ks < 7; ++ks) {
                int kb = ks * 32 + q * 8;
                bf16x8 bf_ = *(const bf16x8*)&BT[(dt * 16 + c) * KST + kb];
                accB = __builtin_amdgcn_mfma_f32_16x16x32_bf16(bf_, bf_, accB, 0, 0, 0);
            }
            if ((c >> 2) == q) nrmB[dt * 16 + c] = accB[c & 3];
            if (dt == 0) {   // wave 4 also does the 16-row A diagonal
                f32x4 accA = (f32x4){0.f, 0.f, 0.f, 0.f};
                for (int ks = 0; ks < 7; ++ks) {
                    int kb = ks * 32 + q * 8;
                    bf16x8 af = *(const bf16x8*)&AT[c * KST + kb];
                    accA = __builtin_amdgcn_mfma_f32_16x16x32_bf16(af, af, accA, 0, 0, 0);
                }
                if ((c >> 2) == q) nrmA[c] = accA[c & 3];
            }
        }
        __syncthreads();   // B2

        // ---- normalize S in place (1024 elems, 2/thread)
        for (int e = t; e < 1024; e += 512) {
            int r_ = e >> 6, cc = e & 63;
            float ns = sqrtf(nrmA[r_]), no = sqrtf(nrmB[cc]);
            S_L[r_ * SST + cc] = S_L[r_ * SST + cc] / fmaxf(ns * no, EPS);
        }
        __syncthreads();   // B3

        // ---- prefetch all three w rows for phase 3 (latency hides under phase 2)
        float wf0[8], wf1[8], wf2[8];
        if (t < 500) {
            int wl = t / 25, wck = t % 25;
            const float* wp0 = (dir ? w2 : w1) + wl * HH + wck * 8;
            const float* wp1 = (dir ? w6 : w5) + wl * HH + wck * 8;
            const float* wp2 = (dir ? w8 : w7) + wl * HH + wck * 8;
            *(float4*)&wf0[0] = *(const float4*)wp0; *(float4*)&wf0[4] = *(const float4*)(wp0 + 4);
            *(float4*)&wf1[0] = *(const float4*)wp1; *(float4*)&wf1[4] = *(const float4*)(wp1 + 4);
            *(float4*)&wf2[0] = *(const float4*)wp2; *(float4*)&wf2[4] = *(const float4*)(wp2 + 4);
        }

        // ---- phase 2: attvec -> meanL / maxL; dsum folded per-thread
        if (t < 400) {
            int s = arow, h0 = ack * 8;
            float sm = 0.f;
            float ms[8], mx[8];
#pragma unroll
            for (int i = 0; i < 8; ++i) { ms[i] = 0.f; mx[i] = -INFINITY; }
            for (int k = 0; k < 64; ++k) {
                float a = S_L[s * SST + k];
                sm += a;
                bf16x8 ov = *(const bf16x8*)&BT[k * KST + h0];
#pragma unroll
                for (int i = 0; i < 8; ++i) {
                    float tt = a * bf2f(ov[i]);
                    ms[i] += tt;
                    mx[i] = fmaxf(mx[i], tt);
                }
            }
            float dsv = fmaxf(sm, EPS);
#pragma unroll
            for (int i = 0; i < 8; ++i) ms[i] /= dsv;
            *(float4*)&meanL[s * MHS + h0]     = *(float4*)&ms[0];
            *(float4*)&meanL[s * MHS + h0 + 4] = *(float4*)&ms[4];
            *(float4*)&maxL[s * MHS + h0]      = *(float4*)&mx[0];
            *(float4*)&maxL[s * MHS + h0 + 4]  = *(float4*)&mx[4];
        }
        __syncthreads();   // B4 — PB/WB overlays about to overwrite AT/BT/S_L

        // ---- phase 3: matches m=0 (full), m=1 (att_mean), m=2 (att_max)
#pragma unroll
        for (int m = 0; m < 3; ++m) {
            // stage products from registers/LDS (no global loads)
            if (t < 400) {
                float yv[8];
                if (m == 0) {
#pragma unroll
                    for (int i = 0; i < 8; ++i) yv[i] = yv0[i];
                } else {
                    const float* yL = (m == 1 ? meanL : maxL) + arow * MHS + ack * 8;
                    *(float4*)&yv[0] = *(const float4*)yL;
                    *(float4*)&yv[4] = *(const float4*)(yL + 4);
                }
                __align__(16) __hip_bfloat16 r1[8], r2[8];
#pragma unroll
                for (int i = 0; i < 8; ++i) {
                    r1[i] = __float2bfloat16(xr[i] * yv[i]);
                    r2[i] = __float2bfloat16(yv[i] * yv[i]);
                }
                if (m == 0) {
                    __align__(16) __hip_bfloat16 r0[8];
#pragma unroll
                    for (int i = 0; i < 8; ++i) r0[i] = __float2bfloat16(xr[i] * xr[i]);
                    *(bf16x8*)&PB[(0 * 16 + arow) * KST + ack * 8] = *(bf16x8*)r0;
                }
                *(bf16x8*)&PB[(1 * 16 + arow) * KST + ack * 8] = *(bf16x8*)r1;
                *(bf16x8*)&PB[(2 * 16 + arow) * KST + ack * 8] = *(bf16x8*)r2;
            }
            // stage w^2 from registers
            if (t < 500) {
                int wl = t / 25, wck = t % 25;
                __align__(16) __hip_bfloat16 wr[8];
                if (m == 0) {
#pragma unroll
                    for (int i = 0; i < 8; ++i) wr[i] = __float2bfloat16(wf0[i] * wf0[i]);
                } else if (m == 1) {
#pragma unroll
                    for (int i = 0; i < 8; ++i) wr[i] = __float2bfloat16(wf1[i] * wf1[i]);
                } else {
#pragma unroll
                    for (int i = 0; i < 8; ++i) wr[i] = __float2bfloat16(wf2[i] * wf2[i]);
                }
                *(bf16x8*)&WB[wl * KST + wck * 8] = *(bf16x8*)wr;
            }
            if (m == 0) {
                // one-time zeros: PB pads (144), WB rows 20-31 (336), WB rows 0-19 pads (60)
                __align__(16) __hip_bfloat16 z8[8];
#pragma unroll
                for (int i = 0; i < 8; ++i) z8[i] = __float2bfloat16(0.f);
                for (int e = t; e < 540; e += 512) {
                    if (e < 144) { int row = e / 3, ckp = 25 + e % 3;
                        *(bf16x8*)&PB[row * KST + ckp * 8] = *(bf16x8*)z8;
                    } else if (e < 480) { int e2 = e - 144; int row = 20 + e2 / 28, ckp = e2 % 28;
                        *(bf16x8*)&WB[row * KST + ckp * 8] = *(bf16x8*)z8;
                    } else { int e2 = e - 480; int row = e2 / 3, ckp = 25 + e2 % 3;
                        *(bf16x8*)&WB[row * KST + ckp * 8] = *(bf16x8*)z8;
                    }
                }
            }
            __syncthreads();

            if (wv_ < 2) {
                int ntile = wv_;
                f32x4 accA = (f32x4){0.f, 0.f, 0.f, 0.f};
                f32x4 accD = (f32x4){0.f, 0.f, 0.f, 0.f};
                f32x4 accB = (f32x4){0.f, 0.f, 0.f, 0.f};
                for (int ks = 0; ks < 7; ++ks) {
                    int kb = ks * 32 + q * 8;
                    bf16x8 bfw = *(const bf16x8*)&WB[(ntile * 16 + c) * KST + kb];
                    bf16x8 a0 = *(const bf16x8*)&PB[(0 * 16 + c) * KST + kb];
                    bf16x8 a1 = *(const bf16x8*)&PB[(1 * 16 + c) * KST + kb];
                    bf16x8 a2 = *(const bf16x8*)&PB[(2 * 16 + c) * KST + kb];
                    accA = __builtin_amdgcn_mfma_f32_16x16x32_bf16(a0, bfw, accA, 0, 0, 0);
                    accD = __builtin_amdgcn_mfma_f32_16x16x32_bf16(a1, bfw, accD, 0, 0, 0);
                    accB = __builtin_amdgcn_mfma_f32_16x16x32_bf16(a2, bfw, accB, 0, 0, 0);
                }
                int l_ = ntile * 16 + c;
                if (l_ < LL) {
                    int chunk = (m == 0) ? 0 : (m == 1) ? 40 : 60;
#pragma unroll
                    for (int r = 0; r < 4; ++r) {
                        int s = qh * 16 + q * 4 + r;
                        float cosv = accD[r] / fmaxf(sqrtf(accA[r] * accB[r]), EPS);
                        out[side * (BB * SS * 160) + (b * SS + s) * 160 + dir * 80 + chunk + l_] = cosv;
                    }
                }
            }
            if (m < 2) __syncthreads();
        }
    } else {
        // ================================ type C: pairwise bf16 MFMA, diag norms
        __hip_bfloat16* AT = (__hip_bfloat16*)smem;            // 64*KST bf16
        __hip_bfloat16* BT = (__hip_bfloat16*)(smem + 7424);   // 64*KST bf16
        float* cmL = smem + 14848;                             // 256 fl
        float* nA  = smem + 15104;                             // 64
        float* nB  = smem + 15168;                             // 64
        int blk = grp * 5 + (rem - 2);   // 0..1279
        int l = blk % LL; int db = blk / LL; int b = db & 31; int dir = db >> 5;

        const float* wrow = (dir ? w4 : w3) + l * HH;
        const float* Ag = conp + dir * HH;
        const float* Bg = conh + dir * HH;

        for (int e = t; e < 64 * 28; e += 512) {
            int m = e / 28, ck = e - m * 28;
            int k = ck * 8;
            __align__(16) __hip_bfloat16 at8[8];
            __align__(16) __hip_bfloat16 bt8[8];
            if (k < HH) {
                const float* ap = Ag + (b * SS + m) * (2 * HH) + k;
                const float* bp = Bg + (b * SS + m) * (2 * HH) + k;
                const float* wp = wrow + k;
                float av[8], bv[8], wvv[8];
                *(float4*)&av[0]  = *(const float4*)ap; *(float4*)&av[4]  = *(const float4*)(ap + 4);
                *(float4*)&bv[0]  = *(const float4*)bp; *(float4*)&bv[4]  = *(const float4*)(bp + 4);
                *(float4*)&wvv[0] = *(const float4*)wp; *(float4*)&wvv[4] = *(const float4*)(wp + 4);
#pragma unroll
                for (int i = 0; i < 8; ++i) {
                    at8[i] = __float2bfloat16(av[i] * wvv[i]);
                    bt8[i] = __float2bfloat16(bv[i] * wvv[i]);
                }
            } else {
#pragma unroll
                for (int ii = 0; ii < 8; ++ii) { at8[ii] = __float2bfloat16(0.f); bt8[ii] = __float2bfloat16(0.f); }
            }
            *(bf16x8*)&AT[m * KST + k] = *(bf16x8*)at8;
            *(bf16x8*)&BT[m * KST + k] = *(bf16x8*)bt8;
        }
        __syncthreads();   // B1

        int wv_ = __builtin_amdgcn_readfirstlane(t >> 6);
        int lane = t & 63;
        int q = lane >> 4, c = lane & 15;
        int m0 = wv_ * 16;

        f32x4 acc[4];
#pragma unroll
        for (int ct = 0; ct < 4; ++ct) acc[ct] = (f32x4){0.f, 0.f, 0.f, 0.f};

        if (wv_ < 4) {
            for (int ks = 0; ks < 7; ++ks) {
                int kb = ks * 32 + q * 8;
                bf16x8 af = *(const bf16x8*)&AT[(m0 + c) * KST + kb];
#pragma unroll
                for (int ct = 0; ct < 4; ++ct) {
                    bf16x8 bf_ = *(const bf16x8*)&BT[(ct * 16 + c) * KST + kb];
                    acc[ct] = __builtin_amdgcn_mfma_f32_16x16x32_bf16(af, bf_, acc[ct], 0, 0, 0);
                }
            }
        } else {
            int d0 = (wv_ - 4) * 16;
            f32x4 accA = (f32x4){0.f, 0.f, 0.f, 0.f};
            f32x4 accB = (f32x4){0.f, 0.f, 0.f, 0.f};
            for (int ks = 0; ks < 7; ++ks) {
                int kb = ks * 32 + q * 8;
                bf16x8 af = *(const bf16x8*)&AT[(d0 + c) * KST + kb];
                bf16x8 bf_ = *(const bf16x8*)&BT[(d0 + c) * KST + kb];
                accA = __builtin_amdgcn_mfma_f32_16x16x32_bf16(af, af, accA, 0, 0, 0);
                accB = __builtin_amdgcn_mfma_f32_16x16x32_bf16(bf_, bf_, accB, 0, 0, 0);
            }
            if ((c >> 2) == q) { nA[d0 + c] = accA[c & 3]; nB[d0 + c] = accB[c & 3]; }
        }
        __syncthreads();   // B2 — diag norms visible

        if (wv_ < 4) {
            float na[4], nb[4];
#pragma unroll
            for (int r = 0; r < 4; ++r) na[r] = sqrtf(nA[m0 + q * 4 + r]);
#pragma unroll
            for (int ct = 0; ct < 4; ++ct) nb[ct] = sqrtf(nB[ct * 16 + c]);

            float rowm[4] = {-INFINITY, -INFINITY, -INFINITY, -INFINITY};
            float colm[4] = {-INFINITY, -INFINITY, -INFINITY, -INFINITY};
#pragma unroll
            for (int ct = 0; ct < 4; ++ct) {
#pragma unroll
                for (int r = 0; r < 4; ++r) {
                    float cv = acc[ct][r] / fmaxf(na[r] * nb[ct], EPS);
                    rowm[r] = fmaxf(rowm[r], cv);
                    colm[ct] = fmaxf(colm[ct], cv);
                }
            }

#pragma unroll
            for (int r = 0; r < 4; ++r) {
                float v = rowm[r];
                v = fmaxf(v, __shfl_xor(v, 1, 64));
                v = fmaxf(v, __shfl_xor(v, 2, 64));
                v = fmaxf(v, __shfl_xor(v, 4, 64));
                v = fmaxf(v, __shfl_xor(v, 8, 64));
                rowm[r] = v;
            }
            if (c == 0) {
#pragma unroll
                for (int r = 0; r < 4; ++r) {
                    int i = m0 + q * 4 + r;
                    out[(b * SS + i) * 160 + dir * 80 + 20 + l] = rowm[r];
                }
            }

#pragma unroll
            for (int ct = 0; ct < 4; ++ct) {
                float v = colm[ct];
                v = fmaxf(v, __shfl_xor(v, 16, 64));
                v = fmaxf(v, __shfl_xor(v, 32, 64));
                colm[ct] = v;
            }
            if (q == 0) {
#pragma unroll
                for (int ct = 0; ct < 4; ++ct) cmL[wv_ * 64 + ct * 16 + c] = colm[ct];
            }
        }
        __syncthreads();   // B3
        if (t < 64) {
            float m = fmaxf(fmaxf(cmL[t], cmL[64 + t]), fmaxf(cmL[128 + t], cmL[192 + t]));
            out[BB * SS * 160 + (b * SS + t) * 160 + dir * 80 + 20 + l] = m;
        }
    }
}

extern "C" void kernel_launch(void* const* d_in, const int* in_sizes, int n_in,
                              void* d_out, int out_size, void* d_ws, size_t ws_size,
                              hipStream_t stream) {
    const float* conp = (const float*)d_in[0];
    const float* conh = (const float*)d_in[1];
    const float* w1 = (const float*)d_in[2];
    const float* w2 = (const float*)d_in[3];
    const float* w3 = (const float*)d_in[4];
    const float* w4 = (const float*)d_in[5];
    const float* w5 = (const float*)d_in[6];
    const float* w6 = (const float*)d_in[7];
    const float* w7 = (const float*)d_in[8];
    const float* w8 = (const float*)d_in[9];
    float* out = (float*)d_out;
    (void)d_ws; (void)ws_size;

    fused_all_kernel<<<1792, 512, 0, stream>>>(conp, conh,
                                               w1, w2, w3, w4, w5, w6, w7, w8, out);
}